// Round 5
// baseline (298.351 us; speedup 1.0000x reference)
//
#include <hip/hip_runtime.h>

#define KK 64
#define TT 1024
#define BB 256
#define START_TAG 0

typedef float v2f __attribute__((ext_vector_type(2)));
typedef float v4f __attribute__((ext_vector_type(4)));

__device__ __forceinline__ float lane_bcast(float v, int lane) {
    return __int_as_float(__builtin_amdgcn_readlane(__float_as_int(v), lane));
}

// Packed dual-fp32 VALU ops (VOP3P). Non-volatile register-only asm: the
// scheduler may interleave freely with ds_read waitcnts.
#define PKMUL(D, S, E) asm("v_pk_mul_f32 %0, %1, %2"     : "=v"(D) : "v"(S), "v"(E));
#define PKFMA(D, S, E) asm("v_pk_fma_f32 %0, %1, %2, %0" : "+v"(D) : "v"(S), "v"(E));
#define PKADD(D, X, Y) asm("v_pk_add_f32 %0, %1, %2"     : "=v"(D) : "v"(X), "v"(Y));

// DPP row-rotate (within the 16-lane row) applied directly to the fmac
// source: delivers one own-row neighbor value per fmac with ZERO gather
// instructions. The rotate-direction convention is resolved at runtime:
// setup rotates the lane-id vector with the SAME dpp control and gathers
// exp(trans) at the resulting indices, so et always matches the HW mapping.
#define RORMOVI(D, K) \
    asm("v_mov_b32 %0, %1 row_ror:" #K " row_mask:0xf bank_mask:0xf" \
        : "=v"(D) : "v"(lid));
#define RORMUL(D, K, E) \
    asm("v_mul_f32 %0, %1, %2 row_ror:" #K " row_mask:0xf bank_mask:0xf" \
        : "=v"(D) : "v"(a), "v"(E));
#define RORFMA(D, K, E) \
    asm("v_fmac_f32 %0, %1, %2 row_ror:" #K " row_mask:0xf bank_mask:0xf" \
        : "+v"(D) : "v"(a), "v"(E));

// One recurrence step (~64 instructions), designed so the VALU works during
// the DS round trip:
//   1 ds_write_b32 (scatter a[i])
//  12 ds_read_b128 (other 3 rows, 4 broadcast addrs 64B apart = 2-way = free)
//  16 own-row MACs via DPP row_ror fmacs on `a` (issued while reads fly)
//  24 pk_fma (48 MACs) consuming the b128 stream as it returns in-order
//   tree + scale + mask select (+ renorm every 4th step)
// Single wave, no barrier: per-wave DS ops execute in order, so the wave's
// own write is visible to its subsequent reads.
#define DO_STEP(EFV, MKV, RN) { \
    abuf[i] = a; \
    const v4f* pA_ = reinterpret_cast<const v4f*>(abuf + cb1); \
    const v4f* pB_ = reinterpret_cast<const v4f*>(abuf + cb2); \
    const v4f* pC_ = reinterpret_cast<const v4f*>(abuf + cb3); \
    v4f wA0 = pA_[0], wA1 = pA_[1], wA2 = pA_[2], wA3 = pA_[3]; \
    v4f wB0 = pB_[0], wB1 = pB_[1], wB2 = pB_[2], wB3 = pB_[3]; \
    v4f wC0 = pC_[0], wC1 = pC_[1], wC2 = pC_[2], wC3 = pC_[3]; \
    float sA = a * er0; \
    float sB; RORMUL(sB, 1, er1) \
    RORFMA(sA, 2,  er2)  RORFMA(sB, 3,  er3) \
    RORFMA(sA, 4,  er4)  RORFMA(sB, 5,  er5) \
    RORFMA(sA, 6,  er6)  RORFMA(sB, 7,  er7) \
    RORFMA(sA, 8,  er8)  RORFMA(sB, 9,  er9) \
    RORFMA(sA, 10, er10) RORFMA(sB, 11, er11) \
    RORFMA(sA, 12, er12) RORFMA(sB, 13, er13) \
    RORFMA(sA, 14, er14) RORFMA(sB, 15, er15) \
    v2f q0, q1, q2, q3; \
    PKMUL(q0, wA0.xy, eA0) PKMUL(q1, wA0.zw, eA1) \
    PKMUL(q2, wA1.xy, eA2) PKMUL(q3, wA1.zw, eA3) \
    PKFMA(q0, wA2.xy, eA4) PKFMA(q1, wA2.zw, eA5) \
    PKFMA(q2, wA3.xy, eA6) PKFMA(q3, wA3.zw, eA7) \
    PKFMA(q0, wB0.xy, eB0) PKFMA(q1, wB0.zw, eB1) \
    PKFMA(q2, wB1.xy, eB2) PKFMA(q3, wB1.zw, eB3) \
    PKFMA(q0, wB2.xy, eB4) PKFMA(q1, wB2.zw, eB5) \
    PKFMA(q2, wB3.xy, eB6) PKFMA(q3, wB3.zw, eB7) \
    PKFMA(q0, wC0.xy, eC0) PKFMA(q1, wC0.zw, eC1) \
    PKFMA(q2, wC1.xy, eC2) PKFMA(q3, wC1.zw, eC3) \
    PKFMA(q0, wC2.xy, eC4) PKFMA(q1, wC2.zw, eC5) \
    PKFMA(q2, wC3.xy, eC6) PKFMA(q3, wC3.zw, eC7) \
    v2f qA, qB, qC; \
    PKADD(qA, q0, q1) PKADD(qB, q2, q3) PKADD(qC, qA, qB) \
    float s_ = (qC.x + qC.y) + (sA + sB); \
    float anew = s_ * (EFV); \
    a = ((MKV) != 0.0f) ? anew : a; \
    if (RN) { \
        float a1 = fmaxf(lane_bcast(a, 1), 1e-37f); \
        a *= __builtin_amdgcn_rcpf(a1); \
        offset += __logf(a1); \
    } \
    asm volatile("s_nop 1" : "+v"(a)); /* VALU-write -> DPP-read fence; also \
        data-blocks hoisting any DPP fmac above the write of a */ \
}

#define PIN4(p,q,r,s) asm volatile("" : "+v"(p), "+v"(q), "+v"(r), "+v"(s));

// Forward algorithm in the probability domain. One wave per batch element;
// lane i owns state i. Model from rounds 0-4: cyc/step ~= 4*insts +
// exposed-DS-latency. This version minimizes BOTH: 13 DS ops (vs 17) and
// the own-row DPP fmacs execute during the DS startup latency.
// Renorm once per 4 steps by a[1] (wave-uniform positive scale is exact
// via offset += log(scale)).
__global__ __launch_bounds__(64)
__attribute__((amdgpu_waves_per_eu(1, 1)))
void crf_forward_kernel(
    const float* __restrict__ feats,
    const float* __restrict__ trans,
    const float* __restrict__ masks,
    const int*   __restrict__ tags,
    float* __restrict__ out)
{
    const int b = blockIdx.x;
    const int i = threadIdx.x;
    const int r = (i >> 4) & 3;        // 16-lane row id
    const int rowbase = i & 48;        // first state of own row

    __shared__ __align__(16) float abuf[KK];

    const float* trow = trans + i * KK;

    // --- own-row et in HW rotate order (direction-proof construction) ---
    int lid = i & 15;
    asm volatile("s_nop 1" : "+v"(lid));   // VALU-write -> DPP-read guard
    int x1, x2, x3, x4, x5, x6, x7, x8, x9, x10, x11, x12, x13, x14, x15;
    RORMOVI(x1, 1)   RORMOVI(x2, 2)   RORMOVI(x3, 3)   RORMOVI(x4, 4)
    RORMOVI(x5, 5)   RORMOVI(x6, 6)   RORMOVI(x7, 7)   RORMOVI(x8, 8)
    RORMOVI(x9, 9)   RORMOVI(x10, 10) RORMOVI(x11, 11) RORMOVI(x12, 12)
    RORMOVI(x13, 13) RORMOVI(x14, 14) RORMOVI(x15, 15)
    float er0  = __expf(trow[rowbase + lid]);
    float er1  = __expf(trow[rowbase + x1]),  er2  = __expf(trow[rowbase + x2]);
    float er3  = __expf(trow[rowbase + x3]),  er4  = __expf(trow[rowbase + x4]);
    float er5  = __expf(trow[rowbase + x5]),  er6  = __expf(trow[rowbase + x6]);
    float er7  = __expf(trow[rowbase + x7]),  er8  = __expf(trow[rowbase + x8]);
    float er9  = __expf(trow[rowbase + x9]),  er10 = __expf(trow[rowbase + x10]);
    float er11 = __expf(trow[rowbase + x11]), er12 = __expf(trow[rowbase + x12]);
    float er13 = __expf(trow[rowbase + x13]), er14 = __expf(trow[rowbase + x14]);
    float er15 = __expf(trow[rowbase + x15]);

    // --- other-rows et pairs, chunk order (r+1, r+2, r+3) mod 4 ---
    const int cb1 = ((r + 1) & 3) << 4;   // float index of chunk base
    const int cb2 = ((r + 2) & 3) << 4;
    const int cb3 = ((r + 3) & 3) << 4;
#define DECLE(nm, cb, p) v2f nm = { __expf(trow[(cb) + 2*(p)]), __expf(trow[(cb) + 2*(p) + 1]) };
    DECLE(eA0, cb1, 0) DECLE(eA1, cb1, 1) DECLE(eA2, cb1, 2) DECLE(eA3, cb1, 3)
    DECLE(eA4, cb1, 4) DECLE(eA5, cb1, 5) DECLE(eA6, cb1, 6) DECLE(eA7, cb1, 7)
    DECLE(eB0, cb2, 0) DECLE(eB1, cb2, 1) DECLE(eB2, cb2, 2) DECLE(eB3, cb2, 3)
    DECLE(eB4, cb2, 4) DECLE(eB5, cb2, 5) DECLE(eB6, cb2, 6) DECLE(eB7, cb2, 7)
    DECLE(eC0, cb3, 0) DECLE(eC1, cb3, 1) DECLE(eC2, cb3, 2) DECLE(eC3, cb3, 3)
    DECLE(eC4, cb3, 4) DECLE(eC5, cb3, 5) DECLE(eC6, cb3, 6) DECLE(eC7, cb3, 7)

    PIN4(er0, er1, er2, er3)   PIN4(er4, er5, er6, er7)
    PIN4(er8, er9, er10, er11) PIN4(er12, er13, er14, er15)
    PIN4(eA0, eA1, eA2, eA3)   PIN4(eA4, eA5, eA6, eA7)
    PIN4(eB0, eB1, eB2, eB3)   PIN4(eB4, eB5, eB6, eB7)
    PIN4(eC0, eC1, eC2, eC3)   PIN4(eC4, eC5, eC6, eC7)

    float a = (i == START_TAG) ? 1.0f : 0.0f;  // exp(alpha0)
    float offset = 0.0f;                        // running log-scale
    asm volatile("s_nop 1" : "+v"(a));          // guard before first DPP use

    const float* fb = feats + (size_t)b * TT * KK;
    const float* mb = masks + (size_t)b * TT;

    // prologue prefetch: steps t = 1..4
    float cf0 = fb[1 * KK + i], cf1 = fb[2 * KK + i];
    float cf2 = fb[3 * KK + i], cf3 = fb[4 * KK + i];
    float cm0 = mb[1], cm1 = mb[2], cm2 = mb[3], cm3 = mb[4];

    // groups t0 = 1,5,...,1021; last group's 4th step (t=1024) masked off
    for (int t0 = 1; t0 < TT; t0 += 4) {
        int p0 = (t0 + 4 < TT) ? t0 + 4 : TT - 1;
        int p1 = (t0 + 5 < TT) ? t0 + 5 : TT - 1;
        int p2 = (t0 + 6 < TT) ? t0 + 6 : TT - 1;
        int p3 = (t0 + 7 < TT) ? t0 + 7 : TT - 1;
        float nf0 = fb[p0 * KK + i], nf1 = fb[p1 * KK + i];
        float nf2 = fb[p2 * KK + i], nf3 = fb[p3 * KK + i];
        float nm0 = mb[p0], nm1 = mb[p1], nm2 = mb[p2], nm3 = mb[p3];

        // exp(feat): inputs prefetched a full group ago -> off critical path
        float ef0 = __expf(cf0), ef1 = __expf(cf1);
        float ef2 = __expf(cf2), ef3 = __expf(cf3);

        DO_STEP(ef0, cm0, 0)
        DO_STEP(ef1, cm1, 0)
        DO_STEP(ef2, cm2, 0)
        float m3 = (t0 + 3 < TT) ? cm3 : 0.0f;   // only last group clips
        DO_STEP(ef3, m3, 1)                       // renorm folded into step 4

        cf0 = nf0; cf1 = nf1; cf2 = nf2; cf3 = nf3;
        cm0 = nm0; cm1 = nm1; cm2 = nm2; cm3 = nm3;
    }

    // forward_score = offset + log(sum_j a_j)
    float s = a;
    #pragma unroll
    for (int off = 32; off >= 1; off >>= 1)
        s += __shfl_xor(s, off, 64);
    float fwd_score = offset + __logf(s);

    // ---- fused gold score: sum_t (trans[ct,pt] + feats[t,ct]) * mask[t] ----
    const int* tg = tags + b * TT;
    float g = 0.f;
    for (int t = 1 + i; t < TT; t += 64) {
        int ct = tg[t], pt = tg[t - 1];
        g += (trans[ct * KK + pt] + fb[t * KK + ct]) * mb[t];
    }
    #pragma unroll
    for (int off = 32; off >= 1; off >>= 1)
        g += __shfl_xor(g, off, 64);

    if (i == 0) atomicAdd(out, (fwd_score - g) * (1.0f / (float)BB));
}

extern "C" void kernel_launch(void* const* d_in, const int* in_sizes, int n_in,
                              void* d_out, int out_size, void* d_ws, size_t ws_size,
                              hipStream_t stream) {
    const float* feats = (const float*)d_in[0];
    const float* trans = (const float*)d_in[1];
    const int*   tags  = (const int*)d_in[2];
    const float* masks = (const float*)d_in[3];
    float* out = (float*)d_out;

    hipMemsetAsync(out, 0, sizeof(float), stream);  // atomicAdd accumulator
    crf_forward_kernel<<<BB, 64, 0, stream>>>(feats, trans, masks, tags, out);
}